// Round 2
// baseline (187.133 us; speedup 1.0000x reference)
//
#include <hip/hip_runtime.h>

using frag_t = __attribute__((ext_vector_type(8))) short;   // 8 x bf16 (4 VGPRs)
using f32x4  = __attribute__((ext_vector_type(4))) float;   // MFMA C/D

#define L2E 1.4426950408889634f

#if __has_builtin(__builtin_amdgcn_exp2f)
#define EXP2(x) __builtin_amdgcn_exp2f(x)   // raw v_exp_f32 (no denormal fixup seq)
#else
#define EXP2(x) exp2f(x)
#endif

constexpr int B_  = 2, S_ = 2048, D_ = 1024, H_ = 16, HD_ = 64;
constexpr int M_  = B_ * S_;      // 4096
constexpr float QSCALE = 0.125f * L2E;   // fold softmax log2e into Q

__device__ __forceinline__ ushort f2bf(float f) {
  union { float f; unsigned u; } v; v.f = f;
  unsigned u = v.u;
  unsigned r = (u + 0x7FFFu + ((u >> 16) & 1u)) >> 16;  // round-nearest-even
  return (ushort)r;
}
__device__ __forceinline__ unsigned pk_bf2(float a, float b) {  // round-half-up pack
  unsigned ua = __float_as_uint(a) + 0x8000u;
  unsigned ub = __float_as_uint(b) + 0x8000u;
  return (ua >> 16) | (ub & 0xFFFF0000u);
}

// async 16B/lane global->LDS (lds dest = wave-uniform base + lane*16) [m97]
__device__ __forceinline__ void gld_lds16(const ushort* g, ushort* l) {
  __builtin_amdgcn_global_load_lds((const __attribute__((address_space(1))) void*)g,
                                   (__attribute__((address_space(3))) void*)l, 16, 0, 0);
}

// ---------- fused prep: x->bf16  |  Wqkv^T->bf16  |  Wproj^T->bf16 ----------
__global__ __launch_bounds__(256) void k_prep(
    const float* __restrict__ x, const float* __restrict__ Wqkv,
    const float* __restrict__ Wproj,
    ushort* __restrict__ Xbf, ushort* __restrict__ Wqt, ushort* __restrict__ Wpt) {
  int blk = blockIdx.x, tid = threadIdx.x;
  if (blk < 1024) {                                 // x convert: 4096 elems/block
    size_t base = (size_t)blk * 4096 + tid * 4;
    #pragma unroll
    for (int i = 0; i < 4; ++i) {
      float4 f = *(const float4*)(x + base + i * 1024);
      ushort4 o;
      o.x = f2bf(f.x); o.y = f2bf(f.y); o.z = f2bf(f.z); o.w = f2bf(f.w);
      *(ushort4*)(Xbf + base + i * 1024) = o;
    }
  } else {                                          // W [K,N] -> W^T [N,K] bf16, 64x64 tile
    __shared__ float tile[64][65];
    const float* in; ushort* out; int N, K, bx, by;
    if (blk < 1024 + 768) { int b2 = blk - 1024; in = Wqkv;  out = Wqt; N = 3072; K = 1024; bx = b2 % 48; by = b2 / 48; }
    else                  { int b2 = blk - 1792; in = Wproj; out = Wpt; N = 1024; K = 1024; bx = b2 % 16; by = b2 / 16; }
    int n0 = bx * 64, k0 = by * 64;
    int tx = tid & 63, ty = tid >> 6;               // (64,4)
    #pragma unroll
    for (int i = 0; i < 16; ++i)
      tile[ty + i * 4][tx] = in[(size_t)(k0 + ty + i * 4) * N + n0 + tx];
    __syncthreads();
    #pragma unroll
    for (int i = 0; i < 16; ++i)
      out[(size_t)(n0 + ty + i * 4) * K + k0 + tx] = f2bf(tile[tx][ty + i * 4]);
  }
}

// ---------- 256x256 8-phase QKV GEMM (m201 template ported to plain HIP) ----------
// R1 post-mortem: ~25 us (vs old ~28) — grid 192/256 CUs + 16-K-tile fill
// overhead caps it; keep, not the binding kernel anymore.
__global__ __launch_bounds__(512, 2) void k_gemm8(
    const ushort* __restrict__ A, const ushort* __restrict__ Bt,
    const float* __restrict__ bias,
    ushort* __restrict__ Qo, ushort* __restrict__ Ko, ushort* __restrict__ Vo) {
  __shared__ ushort smem[65536];                    // 128 KiB
  int tid = threadIdx.x;
  int lane = tid & 63, wave = tid >> 6;
  int quad = lane >> 4, li = lane & 15;
  int wm = wave >> 2, wn = wave & 3;
  int wg = blockIdx.x;                              // 192 = 16(M) x 12(N)
  int swz = (wg & 7) * 24 + (wg >> 3);              // contiguous 24-chunk per XCD
  int by = swz / 12, bx = swz % 12;
  int m0 = by * 256, n0 = bx * 256;
  const ushort* Asrc = A  + (size_t)m0 * 1024;
  const ushort* Bsrc = Bt + (size_t)n0 * 1024;
  int srow   = lane >> 2;                           // 16 rows / gld_lds
  int schunk = (lane & 3) ^ ((lane >> 4) & 3);      // stored pos -> source chunk
  int pos    = (quad ^ ((li >> 2) & 3)) * 8;        // frag read position (elems)

#define STG(BI, ISB, KS, KT) do { \
    const ushort* _s = (ISB) ? Bsrc : Asrc; \
    ushort* _d = &smem[((BI)*4 + (ISB)*2 + (KS)) * 8192]; \
    _Pragma("unroll") \
    for (int j = 0; j < 2; ++j) \
      gld_lds16(&_s[(size_t)(j*128 + wave*16 + srow) * 1024 + (KT)*64 + (KS)*32 + schunk*8], \
                &_d[(j*128 + wave*16) * 32]); \
  } while (0)

  f32x4 acc[8][4] = {};
  frag_t af[8], bf[2];

#define PH(BI, KS, NH, STGS, W4) do { \
    if ((NH) == 0) { \
      _Pragma("unroll") \
      for (int mi = 0; mi < 8; ++mi) \
        af[mi] = *(const frag_t*)&smem[((BI)*4 + (KS)) * 8192 + (wm*128 + mi*16 + li) * 32 + pos]; \
    } \
    _Pragma("unroll") \
    for (int nj = 0; nj < 2; ++nj) \
      bf[nj] = *(const frag_t*)&smem[((BI)*4 + 2 + (KS)) * 8192 + (wn*64 + ((NH)*2 + nj)*16 + li) * 32 + pos]; \
    STGS; \
    if (W4) asm volatile("s_waitcnt vmcnt(4)" ::: "memory"); \
    asm volatile("s_barrier" ::: "memory"); \
    __builtin_amdgcn_s_setprio(1); \
    _Pragma("unroll") \
    for (int mi = 0; mi < 8; ++mi) { \
      acc[mi][(NH)*2+0] = __builtin_amdgcn_mfma_f32_16x16x32_bf16(af[mi], bf[0], acc[mi][(NH)*2+0], 0, 0, 0); \
      acc[mi][(NH)*2+1] = __builtin_amdgcn_mfma_f32_16x16x32_bf16(af[mi], bf[1], acc[mi][(NH)*2+1], 0, 0, 0); \
    } \
    __builtin_amdgcn_s_setprio(0); \
    asm volatile("s_barrier" ::: "memory"); \
  } while (0)

  // prologue: tile0 complete + tile1's K0 halves issued; vmcnt(4) retires
  // exactly tile0 (8 loads), leaves 2 half-tiles (4 loads) in flight.
  STG(0,0,0,0); STG(0,1,0,0); STG(0,0,1,0); STG(0,1,1,0);
  STG(1,0,0,1); STG(1,1,0,1);
  asm volatile("s_waitcnt vmcnt(4)" ::: "memory");
  asm volatile("s_barrier" ::: "memory");

  for (int it = 0; it < 8; ++it) {                  // 2 K-tiles / iter, NT=16
    int t1 = 2*it + 1;
    int t2 = (2*it + 2 < 16) ? 2*it + 2 : 15;       // clamp: dead stage keeps
    int t3 = (2*it + 3 < 16) ? 2*it + 3 : 15;       //   vmcnt counts uniform
    PH(0,0,0, STG(1,0,1,t1), 0);                    // P1: +A[t+1].K1
    PH(0,0,1, STG(1,1,1,t1), 0);                    // P2: +B[t+1].K1
    PH(0,1,0, STG(0,0,0,t2), 0);                    // P3: +A[t+2].K0
    PH(0,1,1, STG(0,1,0,t2), 1);                    // P4: +B[t+2].K0, vmcnt(4)
    PH(1,0,0, STG(0,0,1,t2), 0);                    // P5: +A[t+2].K1
    PH(1,0,1, STG(0,1,1,t2), 0);                    // P6: +B[t+2].K1
    PH(1,1,0, STG(1,0,0,t3), 0);                    // P7: +A[t+3].K0
    PH(1,1,1, STG(1,1,0,t3), 1);                    // P8: +B[t+3].K0, vmcnt(4)
  }
#undef PH
#undef STG

  asm volatile("s_waitcnt vmcnt(0)" ::: "memory");  // drain dead stages before LDS reuse
  __syncthreads();

  // epilogue: C row = quad*4+r, col = li  [m89/m91]; wave tile 128(M)x64(N)
  int which = (n0 + wn * 64) >> 10;                 // wave-uniform: Q/K/V region
  if (which < 2) {                                  // Q / K: [bh][s][hd]
    #pragma unroll
    for (int ni = 0; ni < 4; ++ni) {
      int gcol = n0 + wn * 64 + ni * 16 + li;
      float bv = bias[gcol];
      int d = gcol & 1023, h = d >> 6, hd = d & 63;
      #pragma unroll
      for (int mi = 0; mi < 8; ++mi)
        #pragma unroll
        for (int r = 0; r < 4; ++r) {
          int grow = m0 + wm * 128 + mi * 16 + quad * 4 + r;
          int b = grow >> 11, s = grow & 2047;
          size_t off = (((size_t)b * H_ + h) * S_ + s) * HD_ + hd;
          float v = acc[mi][ni][r] + bv;
          if (which == 0) Qo[off] = f2bf(v * QSCALE);
          else            Ko[off] = f2bf(v);
        }
    }
  } else {                                          // V -> sigma-permuted V^T
    ushort* vl = &smem[wave * 8192];
    #pragma unroll
    for (int ni = 0; ni < 4; ++ni) {
      int row = ni * 16 + li;                       // hd 0..63
      float bv = bias[n0 + wn * 64 + row];
      int rx = (row & 7) << 3;
      #pragma unroll
      for (int mi = 0; mi < 8; ++mi)
        #pragma unroll
        for (int r = 0; r < 4; ++r) {               // sigma(16q+4r+mi') = 16mi'+4q+r
          int col = (mi >> 2) * 64 + quad * 16 + r * 4 + (mi & 3);
          vl[row * 128 + (col ^ rx)] = f2bf(acc[mi][ni][r] + bv);
        }
    }                                               // wave-private: in-order ds
    int h  = ((n0 & 1023) + wn * 64) >> 6;          // head (wave n-range = 1 head)
    int b  = m0 >> 11;
    int s0 = (m0 & 2047) + wm * 128;                // wave's 128-key span (64-aligned)
    size_t vbase = ((size_t)b * H_ + h) * HD_ * S_;
    #pragma unroll
    for (int i = 0; i < 16; ++i) {
      int row = i * 4 + quad;                       // hd
      int col = li * 8;                             // permuted s chunk (16B)
      *(uint4*)&Vo[vbase + (size_t)row * S_ + s0 + col] =
          *(const uint4*)&vl[row * 128 + (col ^ ((row & 7) << 3))];
    }
  }
}

// ---------- bf16 MFMA GEMM (m97 structure) — proj epilogue ----------
template <int EPI>
__global__ __launch_bounds__(256) void k_gemm(
    const ushort* __restrict__ A, const ushort* __restrict__ Bt,
    const float* __restrict__ bias,
    float* __restrict__ Co, int N, int K) {
  constexpr int BM = 64;
  constexpr int BN = 64, BK = 64;
  constexpr int MI = 2, NI = 2;
  __shared__ ushort smem[(BM + BN) * BK];
  ushort* As = smem;
  ushort* Bs = smem + BM * BK;
  int tid  = threadIdx.x;
  int lane = tid & 63, wave = tid >> 6;
  int quad = lane >> 4, li = lane & 15;
  int mbase = (wave >> 1) * (MI * 16);              // 2x2 waves
  int nbase = (wave & 1) * 32;
  int m0 = blockIdx.y * BM, n0 = blockIdx.x * BN;
  int srow = lane >> 3;                             // within a wave: 8 rows x 128B
  int scol = ((lane & 7) ^ srow) * 8;               // XOR-swizzled global chunk
  f32x4 acc[MI][NI] = {};
  for (int k0 = 0; k0 < K; k0 += BK) {
    #pragma unroll
    for (int i = 0; i < 2; ++i) {                   // A: 64 rows
      int rbase = wave * 16 + i * 8;
      gld_lds16(&A[(size_t)(m0 + rbase + srow) * K + k0 + scol], &As[rbase * BK]);
    }
    #pragma unroll
    for (int i = 0; i < 2; ++i) {                   // B: 64 rows
      int rbase = wave * 16 + i * 8;
      gld_lds16(&Bt[(size_t)(n0 + rbase + srow) * K + k0 + scol], &Bs[rbase * BK]);
    }
    __syncthreads();                                // drains vmcnt (compiler-emitted)
    #pragma unroll
    for (int ks = 0; ks < 2; ++ks) {
      frag_t af[MI], bf[NI];
      #pragma unroll
      for (int mi = 0; mi < MI; ++mi)
        af[mi] = *(const frag_t*)&As[(mbase + mi * 16 + li) * BK + (((ks * 4 + quad) ^ (li & 7)) * 8)];
      #pragma unroll
      for (int ni = 0; ni < NI; ++ni)
        bf[ni] = *(const frag_t*)&Bs[(nbase + ni * 16 + li) * BK + (((ks * 4 + quad) ^ (li & 7)) * 8)];
      #pragma unroll
      for (int mi = 0; mi < MI; ++mi)
        #pragma unroll
        for (int ni = 0; ni < NI; ++ni)
          acc[mi][ni] = __builtin_amdgcn_mfma_f32_16x16x32_bf16(af[mi], bf[ni], acc[mi][ni], 0, 0, 0);
    }
    __syncthreads();
  }
  // epilogue: C/D layout row = quad*4+reg, col = li  [measured m89/m91]
  #pragma unroll
  for (int mi = 0; mi < MI; ++mi)
    #pragma unroll
    for (int ni = 0; ni < NI; ++ni) {
      int gcol = n0 + nbase + ni * 16 + li;
      float bv = bias[gcol];
      #pragma unroll
      for (int r = 0; r < 4; ++r) {
        int grow = m0 + mbase + mi * 16 + quad * 4 + r;
        Co[(size_t)grow * N + gcol] = acc[mi][ni][r] + bv;
      }
    }
}

// ---------- causal flash attention: 128-row q-tiles, 32 rows/wave ----------
// R2: attn was modeled LDS-BW-bound (kf/vf reads + staging >> MFMA pipe).
// Each wave now owns TWO 16-row halves; kf/vf fragments are read ONCE and
// feed both halves' MFMAs (LDS read bytes/row 1.25KB -> 0.75KB, -40%), and
// each staged 64-key K/V tile serves 128 q-rows (staging events 528 -> 272
// per bh, -48%). sigma-permuted P pack/read unchanged per half (the &6 XOR
// keys ignore the +16h row offset — bit 4 untouched). LDS 48KB -> 3 WG/CU.
// Waves 0-1 skip the final all-masked tile (wave-uniform guard; barrier
// stays outside). l via MFMA ones-B; raw v_exp_f32; log2e folded in Q.
__global__ __launch_bounds__(256) void k_attn(
    const ushort* __restrict__ Q, const ushort* __restrict__ K,
    const ushort* __restrict__ Vt, ushort* __restrict__ O) {
  __shared__ ushort Kbuf[2][64 * 64];
  __shared__ ushort Vbuf[2][64 * 64];
  __shared__ ushort Plds[4 * 32 * 64];             // per-wave 32-row P buffer
  int lane = threadIdx.x & 63, wave = threadIdx.x >> 6;
  int quad = lane >> 4, li = lane & 15;
  int bh = blockIdx.x;                             // x = bh: XCD round-robin, K/V hot in L2
  int qt = 15 - (int)blockIdx.y;                   // heavy q-tiles dispatch first
  int b = bh >> 4, hh = bh & 15;
  int q0 = qt * 128 + wave * 32;                   // wave's 32-row base
  const ushort* Qb = Q  + (size_t)bh * S_ * HD_;
  const ushort* Kb = K  + (size_t)bh * S_ * HD_;
  const ushort* Vb = Vt + (size_t)bh * HD_ * S_;
  ushort* Pw = &Plds[wave * 2048];

  frag_t qf[2][2];  // [half][ks]; A-operand: m = li, k = quad*8+j  [m120]
  #pragma unroll
  for (int h = 0; h < 2; ++h)
    #pragma unroll
    for (int ks = 0; ks < 2; ++ks)
      qf[h][ks] = *(const frag_t*)&Qb[(size_t)(q0 + h * 16 + li) * HD_ + ks * 32 + quad * 8];

  frag_t ones;                                     // bf16 1.0 splat (B for row-sum MFMA)
  #pragma unroll
  for (int i = 0; i < 8; ++i) ones[i] = (short)0x3F80;

  f32x4 o[2][4] = {};
  f32x4 lacc[2] = {};                              // row-sums of P (C-layout, col-broadcast)

  auto stage = [&](int kb, int bi) {
    #pragma unroll
    for (int i = 0; i < 2; ++i) {
      int rt  = wave * 16 + i * 8 + (lane >> 3);   // tile row
      int c16 = (lane & 7) ^ (lane >> 3);          // swizzle: (rt&7) == lane>>3
      gld_lds16(&Kb[(size_t)(kb * 64 + rt) * HD_ + c16 * 8], &Kbuf[bi][(wave * 16 + i * 8) * 64]);
      gld_lds16(&Vb[(size_t)rt * S_ + kb * 64 + c16 * 8],    &Vbuf[bi][(wave * 16 + i * 8) * 64]);
    }
  };

  auto comp = [&](int kb, bool diag, int bi) {
    f32x4 sc[2][4];
    #pragma unroll
    for (int t = 0; t < 4; ++t) {                  // kf read once, feeds both halves
      frag_t kf0 = *(const frag_t*)&Kbuf[bi][(t * 16 + li) * 64 + ((quad ^ (li & 7)) * 8)];
      frag_t kf1 = *(const frag_t*)&Kbuf[bi][(t * 16 + li) * 64 + (((quad + 4) ^ (li & 7)) * 8)];
      #pragma unroll
      for (int h = 0; h < 2; ++h) {
        f32x4 a = {};
        a = __builtin_amdgcn_mfma_f32_16x16x32_bf16(qf[h][0], kf0, a, 0, 0, 0);
        a = __builtin_amdgcn_mfma_f32_16x16x32_bf16(qf[h][1], kf1, a, 0, 0, 0);
        sc[h][t] = a;
      }
    }
    if (diag) {
      #pragma unroll
      for (int h = 0; h < 2; ++h)
        #pragma unroll
        for (int t = 0; t < 4; ++t) {
          int key = kb * 64 + t * 16 + li;
          #pragma unroll
          for (int r = 0; r < 4; ++r)
            if (key > q0 + h * 16 + quad * 4 + r) sc[h][t][r] = -1e30f;
        }
    }
    #pragma unroll
    for (int h = 0; h < 2; ++h)
      #pragma unroll
      for (int t = 0; t < 4; ++t)
        #pragma unroll
        for (int r = 0; r < 4; ++r)
          sc[h][t][r] = EXP2(sc[h][t][r]);         // masked -> exp2(-1e30) = 0
    #pragma unroll
    for (int h = 0; h < 2; ++h)
      #pragma unroll
      for (int r = 0; r < 4; ++r) {                // pack 4 bf16 (permuted cols) -> b64
        int row = quad * 4 + r;
        uint2 w;
        w.x = pk_bf2(sc[h][0][r], sc[h][1][r]);
        w.y = pk_bf2(sc[h][2][r], sc[h][3][r]);
        *(uint2*)&Pw[(h * 16 + row) * 64 + ((li ^ (row & 6)) * 4)] = w;
      }
    frag_t pf[2][2];                               // wave-private LDS: in-order, no barrier
    #pragma unroll
    for (int h = 0; h < 2; ++h)
      #pragma unroll
      for (int ks = 0; ks < 2; ++ks) {
        int g0 = (ks * 4 + quad) * 2;
        pf[h][ks] = *(const frag_t*)&Pw[(h * 16 + li) * 64 + ((g0 ^ (li & 6)) * 4)];
      }
    #pragma unroll
    for (int h = 0; h < 2; ++h) {
      lacc[h] = __builtin_amdgcn_mfma_f32_16x16x32_bf16(pf[h][0], ones, lacc[h], 0, 0, 0);
      lacc[h] = __builtin_amdgcn_mfma_f32_16x16x32_bf16(pf[h][1], ones, lacc[h], 0, 0, 0);
    }
    #pragma unroll
    for (int t = 0; t < 4; ++t)
      #pragma unroll
      for (int ks = 0; ks < 2; ++ks) {             // vf read once, feeds both halves
        frag_t vf = *(const frag_t*)&Vbuf[bi][(t * 16 + li) * 64 + (((quad + ks * 4) ^ (li & 7)) * 8)];
        #pragma unroll
        for (int h = 0; h < 2; ++h)
          o[h][t] = __builtin_amdgcn_mfma_f32_16x16x32_bf16(pf[h][ks], vf, o[h][t], 0, 0, 0);
      }
  };

  stage(0, 0);
  __syncthreads();                                 // DMA for kb=0 landed
  int kmax = 2 * qt + 1;
  for (int kb = 0; kb <= kmax; ++kb) {
    if (kb < kmax) stage(kb + 1, (kb + 1) & 1);    // async DMA overlaps comp below
    if (kb * 64 <= q0 + 31)                        // waves 0-1: skip all-masked last tile
      comp(kb, kb * 64 + 63 > q0, kb & 1);
    __syncthreads();                               // drains DMA + guards buffer reuse
  }

  #pragma unroll
  for (int h = 0; h < 2; ++h)
    #pragma unroll
    for (int r = 0; r < 4; ++r) {
      float inv = 1.f / lacc[h][r];                // row-sum already broadcast across lanes
      int srow = q0 + h * 16 + quad * 4 + r;
      #pragma unroll
      for (int ht = 0; ht < 4; ++ht)
        O[((size_t)b * S_ + srow) * D_ + hh * 64 + ht * 16 + li] = f2bf(o[h][ht][r] * inv);
    }
}

extern "C" void kernel_launch(void* const* d_in, const int* in_sizes, int n_in,
                              void* d_out, int out_size, void* d_ws, size_t ws_size,
                              hipStream_t stream) {
  (void)in_sizes; (void)n_in; (void)out_size; (void)ws_size;
  const float* x     = (const float*)d_in[0];
  const float* Wqkv  = (const float*)d_in[1];
  const float* bqkv  = (const float*)d_in[2];
  const float* Wproj = (const float*)d_in[3];
  const float* bproj = (const float*)d_in[4];
  float* out = (float*)d_out;

  char* ws = (char*)d_ws;                          // 40 MB used
  ushort* Xbf = (ushort*)(ws);                     //  8 MB  [4096,1024] bf16 (reused as O after attn)
  ushort* Wqt = (ushort*)(ws + (8u  << 20));       //  6 MB  [3072,1024] bf16
  ushort* Wpt = (ushort*)(ws + (14u << 20));       //  2 MB  [1024,1024] bf16
  ushort* Qbf = (ushort*)(ws + (16u << 20));       //  8 MB  [32,2048,64]  (pre-scaled by 0.125*log2e)
  ushort* Kbf = (ushort*)(ws + (24u << 20));       //  8 MB  [32,2048,64]
  ushort* Vtb = (ushort*)(ws + (32u << 20));       //  8 MB  [32,64,2048]  (V^T, sigma-permuted keys)
  ushort* Obf = Xbf;                               // X dead after QKV GEMM

  k_prep<<<dim3(2048), dim3(256), 0, stream>>>(x, Wqkv, Wproj, Xbf, Wqt, Wpt);
  k_gemm8<<<dim3(192), dim3(512), 0, stream>>>(Xbf, Wqt, bqkv, Qbf, Kbf, Vtb);
  k_attn<<<dim3(B_ * H_, 16), dim3(256), 0, stream>>>(Qbf, Kbf, Vtb, Obf);
  k_gemm<1><<<dim3(16, 64), dim3(256), 0, stream>>>(Obf, Wpt, bproj, out, D_, D_);
}

// Round 3
// 169.365 us; speedup vs baseline: 1.1049x; 1.1049x over previous
//
#include <hip/hip_runtime.h>

using frag_t = __attribute__((ext_vector_type(8))) short;   // 8 x bf16 (4 VGPRs)
using f32x4  = __attribute__((ext_vector_type(4))) float;   // MFMA C/D

#define L2E 1.4426950408889634f

#if __has_builtin(__builtin_amdgcn_exp2f)
#define EXP2(x) __builtin_amdgcn_exp2f(x)   // raw v_exp_f32 (no denormal fixup seq)
#else
#define EXP2(x) exp2f(x)
#endif

constexpr int B_  = 2, S_ = 2048, D_ = 1024, H_ = 16, HD_ = 64;
constexpr int M_  = B_ * S_;      // 4096
constexpr float QSCALE = 0.125f * L2E;   // fold softmax log2e into Q

__device__ __forceinline__ ushort f2bf(float f) {
  union { float f; unsigned u; } v; v.f = f;
  unsigned u = v.u;
  unsigned r = (u + 0x7FFFu + ((u >> 16) & 1u)) >> 16;  // round-nearest-even
  return (ushort)r;
}

// async 16B/lane global->LDS (lds dest = wave-uniform base + lane*16) [m97]
__device__ __forceinline__ void gld_lds16(const ushort* g, ushort* l) {
  __builtin_amdgcn_global_load_lds((const __attribute__((address_space(1))) void*)g,
                                   (__attribute__((address_space(3))) void*)l, 16, 0, 0);
}

// ---------- fused prep: x->bf16  |  Wqkv^T->bf16  |  Wproj^T->bf16 ----------
__global__ __launch_bounds__(256) void k_prep(
    const float* __restrict__ x, const float* __restrict__ Wqkv,
    const float* __restrict__ Wproj,
    ushort* __restrict__ Xbf, ushort* __restrict__ Wqt, ushort* __restrict__ Wpt) {
  int blk = blockIdx.x, tid = threadIdx.x;
  if (blk < 1024) {                                 // x convert: 4096 elems/block
    size_t base = (size_t)blk * 4096 + tid * 4;
    #pragma unroll
    for (int i = 0; i < 4; ++i) {
      float4 f = *(const float4*)(x + base + i * 1024);
      ushort4 o;
      o.x = f2bf(f.x); o.y = f2bf(f.y); o.z = f2bf(f.z); o.w = f2bf(f.w);
      *(ushort4*)(Xbf + base + i * 1024) = o;
    }
  } else {                                          // W [K,N] -> W^T [N,K] bf16, 64x64 tile
    __shared__ float tile[64][65];
    const float* in; ushort* out; int N, K, bx, by;
    if (blk < 1024 + 768) { int b2 = blk - 1024; in = Wqkv;  out = Wqt; N = 3072; K = 1024; bx = b2 % 48; by = b2 / 48; }
    else                  { int b2 = blk - 1792; in = Wproj; out = Wpt; N = 1024; K = 1024; bx = b2 % 16; by = b2 / 16; }
    int n0 = bx * 64, k0 = by * 64;
    int tx = tid & 63, ty = tid >> 6;               // (64,4)
    #pragma unroll
    for (int i = 0; i < 16; ++i)
      tile[ty + i * 4][tx] = in[(size_t)(k0 + ty + i * 4) * N + n0 + tx];
    __syncthreads();
    #pragma unroll
    for (int i = 0; i < 16; ++i)
      out[(size_t)(n0 + ty + i * 4) * K + k0 + tx] = f2bf(tile[tx][ty + i * 4]);
  }
}

// ---------- 256x256 8-phase QKV GEMM (m201 template ported to plain HIP) ----------
// ~25 us. R3 change: V^T epilogue now stores the permlane-sigma basis
// (within each 32-key block, swap 4-groups 1<->2 of each 16) matching the
// attn kernel's in-register P fragment construction.
__global__ __launch_bounds__(512, 2) void k_gemm8(
    const ushort* __restrict__ A, const ushort* __restrict__ Bt,
    const float* __restrict__ bias,
    ushort* __restrict__ Qo, ushort* __restrict__ Ko, ushort* __restrict__ Vo) {
  __shared__ ushort smem[65536];                    // 128 KiB
  int tid = threadIdx.x;
  int lane = tid & 63, wave = tid >> 6;
  int quad = lane >> 4, li = lane & 15;
  int wm = wave >> 2, wn = wave & 3;
  int wg = blockIdx.x;                              // 192 = 16(M) x 12(N)
  int swz = (wg & 7) * 24 + (wg >> 3);              // contiguous 24-chunk per XCD
  int by = swz / 12, bx = swz % 12;
  int m0 = by * 256, n0 = bx * 256;
  const ushort* Asrc = A  + (size_t)m0 * 1024;
  const ushort* Bsrc = Bt + (size_t)n0 * 1024;
  int srow   = lane >> 2;                           // 16 rows / gld_lds
  int schunk = (lane & 3) ^ ((lane >> 4) & 3);      // stored pos -> source chunk
  int pos    = (quad ^ ((li >> 2) & 3)) * 8;        // frag read position (elems)

#define STG(BI, ISB, KS, KT) do { \
    const ushort* _s = (ISB) ? Bsrc : Asrc; \
    ushort* _d = &smem[((BI)*4 + (ISB)*2 + (KS)) * 8192]; \
    _Pragma("unroll") \
    for (int j = 0; j < 2; ++j) \
      gld_lds16(&_s[(size_t)(j*128 + wave*16 + srow) * 1024 + (KT)*64 + (KS)*32 + schunk*8], \
                &_d[(j*128 + wave*16) * 32]); \
  } while (0)

  f32x4 acc[8][4] = {};
  frag_t af[8], bf[2];

#define PH(BI, KS, NH, STGS, W4) do { \
    if ((NH) == 0) { \
      _Pragma("unroll") \
      for (int mi = 0; mi < 8; ++mi) \
        af[mi] = *(const frag_t*)&smem[((BI)*4 + (KS)) * 8192 + (wm*128 + mi*16 + li) * 32 + pos]; \
    } \
    _Pragma("unroll") \
    for (int nj = 0; nj < 2; ++nj) \
      bf[nj] = *(const frag_t*)&smem[((BI)*4 + 2 + (KS)) * 8192 + (wn*64 + ((NH)*2 + nj)*16 + li) * 32 + pos]; \
    STGS; \
    if (W4) asm volatile("s_waitcnt vmcnt(4)" ::: "memory"); \
    asm volatile("s_barrier" ::: "memory"); \
    __builtin_amdgcn_s_setprio(1); \
    _Pragma("unroll") \
    for (int mi = 0; mi < 8; ++mi) { \
      acc[mi][(NH)*2+0] = __builtin_amdgcn_mfma_f32_16x16x32_bf16(af[mi], bf[0], acc[mi][(NH)*2+0], 0, 0, 0); \
      acc[mi][(NH)*2+1] = __builtin_amdgcn_mfma_f32_16x16x32_bf16(af[mi], bf[1], acc[mi][(NH)*2+1], 0, 0, 0); \
    } \
    __builtin_amdgcn_s_setprio(0); \
    asm volatile("s_barrier" ::: "memory"); \
  } while (0)

  // prologue: tile0 complete + tile1's K0 halves issued; vmcnt(4) retires
  // exactly tile0 (8 loads), leaves 2 half-tiles (4 loads) in flight.
  STG(0,0,0,0); STG(0,1,0,0); STG(0,0,1,0); STG(0,1,1,0);
  STG(1,0,0,1); STG(1,1,0,1);
  asm volatile("s_waitcnt vmcnt(4)" ::: "memory");
  asm volatile("s_barrier" ::: "memory");

  for (int it = 0; it < 8; ++it) {                  // 2 K-tiles / iter, NT=16
    int t1 = 2*it + 1;
    int t2 = (2*it + 2 < 16) ? 2*it + 2 : 15;       // clamp: dead stage keeps
    int t3 = (2*it + 3 < 16) ? 2*it + 3 : 15;       //   vmcnt counts uniform
    PH(0,0,0, STG(1,0,1,t1), 0);                    // P1: +A[t+1].K1
    PH(0,0,1, STG(1,1,1,t1), 0);                    // P2: +B[t+1].K1
    PH(0,1,0, STG(0,0,0,t2), 0);                    // P3: +A[t+2].K0
    PH(0,1,1, STG(0,1,0,t2), 1);                    // P4: +B[t+2].K0, vmcnt(4)
    PH(1,0,0, STG(0,0,1,t2), 0);                    // P5: +A[t+2].K1
    PH(1,0,1, STG(0,1,1,t2), 0);                    // P6: +B[t+2].K1
    PH(1,1,0, STG(1,0,0,t3), 0);                    // P7: +A[t+3].K0
    PH(1,1,1, STG(1,1,0,t3), 1);                    // P8: +B[t+3].K0, vmcnt(4)
  }
#undef PH
#undef STG

  asm volatile("s_waitcnt vmcnt(0)" ::: "memory");  // drain dead stages before LDS reuse
  __syncthreads();

  // epilogue: C row = quad*4+r, col = li  [m89/m91]; wave tile 128(M)x64(N)
  int which = (n0 + wn * 64) >> 10;                 // wave-uniform: Q/K/V region
  if (which < 2) {                                  // Q / K: [bh][s][hd]
    #pragma unroll
    for (int ni = 0; ni < 4; ++ni) {
      int gcol = n0 + wn * 64 + ni * 16 + li;
      float bv = bias[gcol];
      int d = gcol & 1023, h = d >> 6, hd = d & 63;
      #pragma unroll
      for (int mi = 0; mi < 8; ++mi)
        #pragma unroll
        for (int r = 0; r < 4; ++r) {
          int grow = m0 + wm * 128 + mi * 16 + quad * 4 + r;
          int b = grow >> 11, s = grow & 2047;
          size_t off = (((size_t)b * H_ + h) * S_ + s) * HD_ + hd;
          float v = acc[mi][ni][r] + bv;
          if (which == 0) Qo[off] = f2bf(v * QSCALE);
          else            Ko[off] = f2bf(v);
        }
    }
  } else {                                          // V -> sigma-permuted V^T
    // natural key n = mi*16 + quad*4 + r (within wave's 128-span); stored at
    // position p = sigma(n): within each 32-block, swap 4-groups 1<->2 of
    // each 16 (involution). Matches attn's permlane32_swap frag basis.
    ushort* vl = &smem[wave * 8192];
    #pragma unroll
    for (int ni = 0; ni < 4; ++ni) {
      int row = ni * 16 + li;                       // hd 0..63
      float bv = bias[n0 + wn * 64 + row];
      int rx = (row & 7) << 3;
      #pragma unroll
      for (int mi = 0; mi < 8; ++mi) {
        int g  = (mi & 1) * 4 + quad;               // 4-group index within 32
        int gm = g & 3;
        int gp = (gm == 1 || gm == 2) ? (g ^ 3) : g;
        #pragma unroll
        for (int r = 0; r < 4; ++r) {
          int col = (mi >> 1) * 32 + gp * 4 + r;    // sigma(n)
          vl[row * 128 + (col ^ rx)] = f2bf(acc[mi][ni][r] + bv);
        }
      }
    }                                               // wave-private: in-order ds
    int h  = ((n0 & 1023) + wn * 64) >> 6;          // head (wave n-range = 1 head)
    int b  = m0 >> 11;
    int s0 = (m0 & 2047) + wm * 128;                // wave's 128-key span (64-aligned)
    size_t vbase = ((size_t)b * H_ + h) * HD_ * S_;
    #pragma unroll
    for (int i = 0; i < 16; ++i) {
      int row = i * 4 + quad;                       // hd
      int col = li * 8;                             // permuted s chunk (16B)
      *(uint4*)&Vo[vbase + (size_t)row * S_ + s0 + col] =
          *(const uint4*)&vl[row * 128 + (col ^ ((row & 7) << 3))];
    }
  }
}

// ---------- bf16 MFMA GEMM (m97 structure) — proj epilogue ----------
template <int EPI>
__global__ __launch_bounds__(256) void k_gemm(
    const ushort* __restrict__ A, const ushort* __restrict__ Bt,
    const float* __restrict__ bias,
    float* __restrict__ Co, int N, int K) {
  constexpr int BM = 64;
  constexpr int BN = 64, BK = 64;
  constexpr int MI = 2, NI = 2;
  __shared__ ushort smem[(BM + BN) * BK];
  ushort* As = smem;
  ushort* Bs = smem + BM * BK;
  int tid  = threadIdx.x;
  int lane = tid & 63, wave = tid >> 6;
  int quad = lane >> 4, li = lane & 15;
  int mbase = (wave >> 1) * (MI * 16);              // 2x2 waves
  int nbase = (wave & 1) * 32;
  int m0 = blockIdx.y * BM, n0 = blockIdx.x * BN;
  int srow = lane >> 3;                             // within a wave: 8 rows x 128B
  int scol = ((lane & 7) ^ srow) * 8;               // XOR-swizzled global chunk
  f32x4 acc[MI][NI] = {};
  for (int k0 = 0; k0 < K; k0 += BK) {
    #pragma unroll
    for (int i = 0; i < 2; ++i) {                   // A: 64 rows
      int rbase = wave * 16 + i * 8;
      gld_lds16(&A[(size_t)(m0 + rbase + srow) * K + k0 + scol], &As[rbase * BK]);
    }
    #pragma unroll
    for (int i = 0; i < 2; ++i) {                   // B: 64 rows
      int rbase = wave * 16 + i * 8;
      gld_lds16(&Bt[(size_t)(n0 + rbase + srow) * K + k0 + scol], &Bs[rbase * BK]);
    }
    __syncthreads();                                // drains vmcnt (compiler-emitted)
    #pragma unroll
    for (int ks = 0; ks < 2; ++ks) {
      frag_t af[MI], bf[NI];
      #pragma unroll
      for (int mi = 0; mi < MI; ++mi)
        af[mi] = *(const frag_t*)&As[(mbase + mi * 16 + li) * BK + (((ks * 4 + quad) ^ (li & 7)) * 8)];
      #pragma unroll
      for (int ni = 0; ni < NI; ++ni)
        bf[ni] = *(const frag_t*)&Bs[(nbase + ni * 16 + li) * BK + (((ks * 4 + quad) ^ (li & 7)) * 8)];
      #pragma unroll
      for (int mi = 0; mi < MI; ++mi)
        #pragma unroll
        for (int ni = 0; ni < NI; ++ni)
          acc[mi][ni] = __builtin_amdgcn_mfma_f32_16x16x32_bf16(af[mi], bf[ni], acc[mi][ni], 0, 0, 0);
    }
    __syncthreads();
  }
  // epilogue: C/D layout row = quad*4+reg, col = li  [measured m89/m91]
  #pragma unroll
  for (int mi = 0; mi < MI; ++mi)
    #pragma unroll
    for (int ni = 0; ni < NI; ++ni) {
      int gcol = n0 + nbase + ni * 16 + li;
      float bv = bias[gcol];
      #pragma unroll
      for (int r = 0; r < 4; ++r) {
        int grow = m0 + mbase + mi * 16 + quad * 4 + r;
        Co[(size_t)grow * N + gcol] = acc[mi][ni][r] + bv;
      }
    }
}

// ---------- causal flash attention: 64-row q-tiles, swapped QK^T, in-reg P ----------
// R3: back to 1024 WGs (R2's 128-row tiles halved occupancy: 12%, MfmaUtil 14%
// -> latency-bound). T12: compute mfma(K,Q) so P is C-layout [key][q]; build
// the PV B-operand in registers via 8x v_cvt_pk_bf16_f32 + 4x
// v_permlane32_swap_b32 per 64-key tile. Deletes Plds (LDS 40->32KB, 5 WG/CU)
// and the P LDS round-trip (4 ds_write + 2 ds_read_b128 + lgkm waits) from
// the serial chain. Key basis sigma (swap 4-groups 1<->2 per 16 within each
// 32-block) is absorbed into the GEMM V^T epilogue. lacc = mfma(ones, pf):
// column-sum of P = row-sum per q, broadcast across C rows.
__global__ __launch_bounds__(256) void k_attn(
    const ushort* __restrict__ Q, const ushort* __restrict__ K,
    const ushort* __restrict__ Vt, ushort* __restrict__ O) {
  __shared__ ushort Kbuf[2][64 * 64];
  __shared__ ushort Vbuf[2][64 * 64];
  int lane = threadIdx.x & 63, wave = threadIdx.x >> 6;
  int quad = lane >> 4, li = lane & 15;
  int bh = blockIdx.x;                             // x = bh: XCD round-robin, K/V hot in L2
  int qb = 31 - (int)blockIdx.y;                   // heavy q-tiles dispatch first
  int b = bh >> 4, hh = bh & 15;
  int q0 = qb * 64 + wave * 16;
  const ushort* Qb = Q  + (size_t)bh * S_ * HD_;
  const ushort* Kb = K  + (size_t)bh * S_ * HD_;
  const ushort* Vb = Vt + (size_t)bh * HD_ * S_;

  frag_t qf[2];  // B-operand now: n = li (=q), k = quad*8+j — same load as A-op
  #pragma unroll
  for (int ks = 0; ks < 2; ++ks)
    qf[ks] = *(const frag_t*)&Qb[(size_t)(q0 + li) * HD_ + ks * 32 + quad * 8];

  frag_t ones;                                     // bf16 1.0 splat (A for col-sum MFMA)
  #pragma unroll
  for (int i = 0; i < 8; ++i) ones[i] = (short)0x3F80;

  f32x4 o[4] = {};                                 // C[hd][q]: hd=ht*16+quad*4+r, q=li
  f32x4 lacc = {};                                 // P column sums (= per-q denom), row-bcast

  auto stage = [&](int kb, int bi) {
    #pragma unroll
    for (int i = 0; i < 2; ++i) {
      int rt  = wave * 16 + i * 8 + (lane >> 3);   // tile row
      int c16 = (lane & 7) ^ (lane >> 3);          // swizzle: (rt&7) == lane>>3
      gld_lds16(&Kb[(size_t)(kb * 64 + rt) * HD_ + c16 * 8], &Kbuf[bi][(wave * 16 + i * 8) * 64]);
      gld_lds16(&Vb[(size_t)rt * S_ + kb * 64 + c16 * 8],    &Vbuf[bi][(wave * 16 + i * 8) * 64]);
    }
  };

  auto comp = [&](int kb, bool diag, int bi) {
    f32x4 sc[4];                                   // P^T tile: sc[t][r] = P[key=t*16+quad*4+r][q=li]
    #pragma unroll
    for (int t = 0; t < 4; ++t) {
      f32x4 a = {};
      #pragma unroll
      for (int ks = 0; ks < 2; ++ks) {
        frag_t kf = *(const frag_t*)&Kbuf[bi][(t * 16 + li) * 64 + (((quad + ks * 4) ^ (li & 7)) * 8)];
        a = __builtin_amdgcn_mfma_f32_16x16x32_bf16(kf, qf[ks], a, 0, 0, 0);  // swapped QK^T
      }
      sc[t] = a;
    }
    if (diag) {
      #pragma unroll
      for (int t = 0; t < 4; ++t) {
        int key = kb * 64 + t * 16 + quad * 4;
        #pragma unroll
        for (int r = 0; r < 4; ++r)
          if (key + r > q0 + li) sc[t][r] = -1e30f;
      }
    }
    #pragma unroll
    for (int t = 0; t < 4; ++t)
      #pragma unroll
      for (int r = 0; r < 4; ++r)
        sc[t][r] = EXP2(sc[t][r]);                 // masked -> exp2(-1e30) = 0

    // in-register P -> B-operand frags (T12): per ks-half (32 keys = t-pair)
    frag_t pf[2];
    #pragma unroll
    for (int ks = 0; ks < 2; ++ks) {
      unsigned w0e, w1e, w0o, w1o;
      asm("v_cvt_pk_bf16_f32 %0, %1, %2" : "=v"(w0e) : "v"(sc[2*ks][0]),   "v"(sc[2*ks][1]));
      asm("v_cvt_pk_bf16_f32 %0, %1, %2" : "=v"(w1e) : "v"(sc[2*ks][2]),   "v"(sc[2*ks][3]));
      asm("v_cvt_pk_bf16_f32 %0, %1, %2" : "=v"(w0o) : "v"(sc[2*ks+1][0]), "v"(sc[2*ks+1][1]));
      asm("v_cvt_pk_bf16_f32 %0, %1, %2" : "=v"(w1o) : "v"(sc[2*ks+1][2]), "v"(sc[2*ks+1][3]));
      // swap upper32(x) <-> lower32(y): x' = f0/f1 (j0..3), y' = f2/f3 (j4..7)
      asm("v_permlane32_swap_b32 %0, %1" : "+v"(w0e), "+v"(w0o));
      asm("v_permlane32_swap_b32 %0, %1" : "+v"(w1e), "+v"(w1o));
      union { frag_t f; unsigned u[4]; } pu;
      pu.u[0] = w0e; pu.u[1] = w1e; pu.u[2] = w0o; pu.u[3] = w1o;
      pf[ks] = pu.f;
    }
    lacc = __builtin_amdgcn_mfma_f32_16x16x32_bf16(ones, pf[0], lacc, 0, 0, 0);
    lacc = __builtin_amdgcn_mfma_f32_16x16x32_bf16(ones, pf[1], lacc, 0, 0, 0);
    #pragma unroll
    for (int ht = 0; ht < 4; ++ht)
      #pragma unroll
      for (int ks = 0; ks < 2; ++ks) {             // V^T as A-operand (positions = kappa)
        frag_t vtf = *(const frag_t*)&Vbuf[bi][(ht * 16 + li) * 64 + (((ks * 4 + quad) ^ (li & 7)) * 8)];
        o[ht] = __builtin_amdgcn_mfma_f32_16x16x32_bf16(vtf, pf[ks], o[ht], 0, 0, 0);
      }
  };

  stage(0, 0);
  __syncthreads();                                 // DMA for kb=0 landed
  for (int kb = 0; kb <= qb; ++kb) {
    if (kb < qb) stage(kb + 1, (kb + 1) & 1);      // async DMA overlaps comp below
    comp(kb, kb == qb, kb & 1);
    __syncthreads();                               // drains DMA + guards buffer reuse
  }

  float inv = 1.f / lacc[0];                       // denom for q=li (row-broadcast)
  int srow = q0 + li;
  size_t obase = ((size_t)b * S_ + srow) * D_ + hh * 64 + quad * 4;
  #pragma unroll
  for (int ht = 0; ht < 4; ++ht) {                 // hd = ht*16+quad*4+r: 4 contiguous
    unsigned lo, hi;
    asm("v_cvt_pk_bf16_f32 %0, %1, %2" : "=v"(lo) : "v"(o[ht][0] * inv), "v"(o[ht][1] * inv));
    asm("v_cvt_pk_bf16_f32 %0, %1, %2" : "=v"(hi) : "v"(o[ht][2] * inv), "v"(o[ht][3] * inv));
    uint2 w; w.x = lo; w.y = hi;
    *(uint2*)&O[obase + ht * 16] = w;
  }
}

extern "C" void kernel_launch(void* const* d_in, const int* in_sizes, int n_in,
                              void* d_out, int out_size, void* d_ws, size_t ws_size,
                              hipStream_t stream) {
  (void)in_sizes; (void)n_in; (void)out_size; (void)ws_size;
  const float* x     = (const float*)d_in[0];
  const float* Wqkv  = (const float*)d_in[1];
  const float* bqkv  = (const float*)d_in[2];
  const float* Wproj = (const float*)d_in[3];
  const float* bproj = (const float*)d_in[4];
  float* out = (float*)d_out;

  char* ws = (char*)d_ws;                          // 40 MB used
  ushort* Xbf = (ushort*)(ws);                     //  8 MB  [4096,1024] bf16 (reused as O after attn)
  ushort* Wqt = (ushort*)(ws + (8u  << 20));       //  6 MB  [3072,1024] bf16
  ushort* Wpt = (ushort*)(ws + (14u << 20));       //  2 MB  [1024,1024] bf16
  ushort* Qbf = (ushort*)(ws + (16u << 20));       //  8 MB  [32,2048,64]  (pre-scaled by 0.125*log2e)
  ushort* Kbf = (ushort*)(ws + (24u << 20));       //  8 MB  [32,2048,64]
  ushort* Vtb = (ushort*)(ws + (32u << 20));       //  8 MB  [32,64,2048]  (V^T, sigma-permuted keys)
  ushort* Obf = Xbf;                               // X dead after QKV GEMM

  k_prep<<<dim3(2048), dim3(256), 0, stream>>>(x, Wqkv, Wproj, Xbf, Wqt, Wpt);
  k_gemm8<<<dim3(192), dim3(512), 0, stream>>>(Xbf, Wqt, bqkv, Qbf, Kbf, Vtb);
  k_attn<<<dim3(B_ * H_, 32), dim3(256), 0, stream>>>(Qbf, Kbf, Vtb, Obf);
  k_gemm<1><<<dim3(16, 64), dim3(256), 0, stream>>>(Obf, Wpt, bproj, out, D_, D_);
}